// Round 1
// baseline (1304.951 us; speedup 1.0000x reference)
//
#include <hip/hip_runtime.h>
#include <stdint.h>

#define N_NODES 50000
#define N_EDGES 800000
#define HID 128

typedef __attribute__((ext_vector_type(8))) short bf16x8;
typedef __attribute__((ext_vector_type(4))) float f32x4;

// round-half-up fp32 -> bf16 pair, packed into one u32 (x = low half)
__device__ inline uint32_t pack_bf16(float x, float y) {
    uint32_t a = __builtin_bit_cast(uint32_t, x) + 0x8000u;
    uint32_t b = __builtin_bit_cast(uint32_t, y) + 0x8000u;
    return (b & 0xffff0000u) | (a >> 16);
}

__device__ inline unsigned short cvt_bf16(float x) {
    return (unsigned short)((__builtin_bit_cast(uint32_t, x) + 0x8000u) >> 16);
}

// 8 consecutive fp32 (32B aligned) -> bf16x8 fragment
__device__ inline bf16x8 load_row8_bf16(const float* p) {
    const float4* q = (const float4*)p;
    float4 u = q[0], v = q[1];
    union { bf16x8 v8; uint32_t u32[4]; } r;
    r.u32[0] = pack_bf16(u.x, u.y);
    r.u32[1] = pack_bf16(u.z, u.w);
    r.u32[2] = pack_bf16(v.x, v.y);
    r.u32[3] = pack_bf16(v.z, v.w);
    return r.v8;
}

// scaled variant (for h = sums * inv_cnt)
__device__ inline bf16x8 load_row8_bf16_scaled(const float* p, float s) {
    const float4* q = (const float4*)p;
    float4 u = q[0], v = q[1];
    union { bf16x8 v8; uint32_t u32[4]; } r;
    r.u32[0] = pack_bf16(u.x * s, u.y * s);
    r.u32[1] = pack_bf16(u.z * s, u.w * s);
    r.u32[2] = pack_bf16(v.x * s, v.y * s);
    r.u32[3] = pack_bf16(v.z * s, v.w * s);
    return r.v8;
}

// --- prep: shuffle We (384x128) and Wn (256x128) fp32 -> bf16 in MFMA
// B-fragment order: frag index (kk, t), lane l holds B[kk*32 + (l>>4)*8 + j][t*16 + (l&15)]
// stored at ((kk*8 + t)*64 + l)*8 + j.
#define WE_SHUF_ELEMS (12 * 8 * 64 * 8)  // 49152
#define WN_SHUF_ELEMS (8 * 8 * 64 * 8)   // 32768
__global__ void prep_kernel(const float* __restrict__ We, const float* __restrict__ Wn,
                            unsigned short* __restrict__ We_shuf,
                            unsigned short* __restrict__ Wn_shuf) {
    int tid = blockIdx.x * blockDim.x + threadIdx.x;
    if (tid < WE_SHUF_ELEMS) {
        int j = tid & 7, lane = (tid >> 3) & 63, tt = tid >> 9;
        int t = tt & 7, kk = tt >> 3;            // kk in [0,12)
        int k = kk * 32 + (lane >> 4) * 8 + j;
        int n = t * 16 + (lane & 15);
        We_shuf[tid] = cvt_bf16(We[k * HID + n]);
    } else if (tid < WE_SHUF_ELEMS + WN_SHUF_ELEMS) {
        int id = tid - WE_SHUF_ELEMS;
        int j = id & 7, lane = (id >> 3) & 63, tt = id >> 9;
        int t = tt & 7, kk = tt >> 3;            // kk in [0,8)
        int k = kk * 32 + (lane >> 4) * 8 + j;
        int n = t * 16 + (lane & 15);
        Wn_shuf[id] = cvt_bf16(Wn[k * HID + n]);
    }
}

// --- edge kernel: per wave, 32 edges x 128 cols.
// m[e] = relu(concat(nfeats[src], efeats[e], nfeats[dst]) @ We + be)
// out1[e] = m[e] + efeats[e];  atomic sums[dst[e]] += m[e];  cnt[dst[e]] += 1
__global__ __launch_bounds__(256) void edge_kernel(
    const float* __restrict__ nfeats, const float* __restrict__ efeats,
    const int* __restrict__ src, const int* __restrict__ dst,
    const unsigned short* __restrict__ We_shuf, const float* __restrict__ be,
    float* __restrict__ out1, float* __restrict__ sums, float* __restrict__ cnt) {
    int wid = blockIdx.x * 4 + (threadIdx.x >> 6);
    int lane = threadIdx.x & 63;
    int e0 = wid * 32;
    int m = lane & 15, quad = lane >> 4;

    // per-edge degree count (one lane per edge)
    if (lane < 32) atomicAdd(&cnt[dst[e0 + lane]], 1.0f);

    int r0 = e0 + m, r1 = e0 + 16 + m;
    const float* pa0[3], *pa1[3];
    pa0[0] = nfeats + (size_t)src[r0] * HID;
    pa0[1] = efeats + (size_t)r0 * HID;
    pa0[2] = nfeats + (size_t)dst[r0] * HID;
    pa1[0] = nfeats + (size_t)src[r1] * HID;
    pa1[1] = efeats + (size_t)r1 * HID;
    pa1[2] = nfeats + (size_t)dst[r1] * HID;

    f32x4 acc[2][8];
#pragma unroll
    for (int mi = 0; mi < 2; ++mi)
#pragma unroll
        for (int t = 0; t < 8; ++t) acc[mi][t] = (f32x4){0.f, 0.f, 0.f, 0.f};

    const bf16x8* W = (const bf16x8*)We_shuf;

#pragma unroll
    for (int kk = 0; kk < 12; ++kk) {
        int k = kk * 32 + quad * 8;       // wave-uniform segment: k/128 same for all lanes
        int seg = k >> 7, off = k & 127;
        bf16x8 a0 = load_row8_bf16(pa0[seg] + off);
        bf16x8 a1 = load_row8_bf16(pa1[seg] + off);
#pragma unroll
        for (int t = 0; t < 8; ++t) {
            bf16x8 b = W[(kk * 8 + t) * 64 + lane];
            acc[0][t] = __builtin_amdgcn_mfma_f32_16x16x32_bf16(a0, b, acc[0][t], 0, 0, 0);
            acc[1][t] = __builtin_amdgcn_mfma_f32_16x16x32_bf16(a1, b, acc[1][t], 0, 0, 0);
        }
    }

    // bias per column (col n = t*16 + (lane&15))
    float bev[8];
#pragma unroll
    for (int t = 0; t < 8; ++t) bev[t] = be[t * 16 + m];

    // epilogue: C/D layout col = lane&15, row = quad*4 + reg
#pragma unroll
    for (int mi = 0; mi < 2; ++mi) {
#pragma unroll
        for (int r = 0; r < 4; ++r) {
            int e = e0 + mi * 16 + quad * 4 + r;
            int de = dst[e];
            const float* ef = efeats + (size_t)e * HID;
            float* o = out1 + (size_t)e * HID;
            float* srow = sums + (size_t)de * HID;
#pragma unroll
            for (int t = 0; t < 8; ++t) {
                int n = t * 16 + m;
                float v = acc[mi][t][r] + bev[t];
                v = fmaxf(v, 0.0f);
                o[n] = v + ef[n];
                atomicAdd(&srow[n], v);
            }
        }
    }
}

// --- node kernel: per wave, 16 nodes x 128 cols.
// h = sums/max(cnt,1); out0 = relu(concat(nfeats, h) @ Wn + bn) + nfeats
__global__ __launch_bounds__(256) void node_kernel(
    const float* __restrict__ nfeats, const unsigned short* __restrict__ Wn_shuf,
    const float* __restrict__ bn, const float* __restrict__ sums,
    const float* __restrict__ cnt, float* __restrict__ out0) {
    int wid = blockIdx.x * 4 + (threadIdx.x >> 6);
    int n0 = wid * 16;
    if (n0 >= N_NODES) return;
    int lane = threadIdx.x & 63;
    int m = lane & 15, quad = lane >> 4;
    int row = n0 + m;
    float inv = 1.0f / fmaxf(cnt[row], 1.0f);
    const float* pn = nfeats + (size_t)row * HID;
    const float* ps = sums + (size_t)row * HID;

    f32x4 acc[8];
#pragma unroll
    for (int t = 0; t < 8; ++t) acc[t] = (f32x4){0.f, 0.f, 0.f, 0.f};

    const bf16x8* W = (const bf16x8*)Wn_shuf;

#pragma unroll
    for (int kk = 0; kk < 8; ++kk) {
        int k = kk * 32 + quad * 8;   // segment (k<128 vs >=128) wave-uniform per kk
        bf16x8 a = (k < 128) ? load_row8_bf16(pn + k)
                             : load_row8_bf16_scaled(ps + (k - 128), inv);
#pragma unroll
        for (int t = 0; t < 8; ++t) {
            bf16x8 b = W[(kk * 8 + t) * 64 + lane];
            acc[t] = __builtin_amdgcn_mfma_f32_16x16x32_bf16(a, b, acc[t], 0, 0, 0);
        }
    }

    float bnv[8];
#pragma unroll
    for (int t = 0; t < 8; ++t) bnv[t] = bn[t * 16 + m];

#pragma unroll
    for (int r = 0; r < 4; ++r) {
        int rw = n0 + quad * 4 + r;
        const float* nf = nfeats + (size_t)rw * HID;
        float* o = out0 + (size_t)rw * HID;
#pragma unroll
        for (int t = 0; t < 8; ++t) {
            int n = t * 16 + m;
            float v = fmaxf(acc[t][r] + bnv[t], 0.0f);
            o[n] = v + nf[n];
        }
    }
}

extern "C" void kernel_launch(void* const* d_in, const int* in_sizes, int n_in,
                              void* d_out, int out_size, void* d_ws, size_t ws_size,
                              hipStream_t stream) {
    const float* nfeats = (const float*)d_in[0];
    const float* efeats = (const float*)d_in[1];
    const int* src = (const int*)d_in[2];
    const int* dst = (const int*)d_in[3];
    const float* We = (const float*)d_in[4];
    const float* be = (const float*)d_in[5];
    const float* Wn = (const float*)d_in[6];
    const float* bn = (const float*)d_in[7];

    float* out0 = (float*)d_out;                       // [N_NODES, HID]
    float* out1 = out0 + (size_t)N_NODES * HID;        // [N_EDGES, HID]

    // workspace: sums (N*H fp32) | cnt (N fp32) | We_shuf (bf16) | Wn_shuf (bf16)
    float* sums = (float*)d_ws;
    float* cnt = sums + (size_t)N_NODES * HID;
    unsigned short* We_shuf = (unsigned short*)(cnt + N_NODES);  // byte off 25,800,000 (16B aligned)
    unsigned short* Wn_shuf = We_shuf + WE_SHUF_ELEMS;

    // zero the accumulators (ws is poisoned 0xAA before every launch)
    hipMemsetAsync(d_ws, 0, ((size_t)N_NODES * HID + N_NODES) * sizeof(float), stream);

    prep_kernel<<<(WE_SHUF_ELEMS + WN_SHUF_ELEMS) / 256, 256, 0, stream>>>(We, Wn, We_shuf, Wn_shuf);

    // 800000 edges / 32 per wave = 25000 waves / 4 per block = 6250 blocks
    edge_kernel<<<6250, 256, 0, stream>>>(nfeats, efeats, src, dst, We_shuf, be, out1, sums, cnt);

    // 50000 nodes / 16 per wave = 3125 waves -> 782 blocks (guarded)
    node_kernel<<<782, 256, 0, stream>>>(nfeats, Wn_shuf, bn, sums, cnt, out0);
}